// Round 7
// baseline (187.090 us; speedup 1.0000x reference)
//
#include <hip/hip_runtime.h>
#include <cstdint>

#define B_   16
#define T_   2048
#define CIN  96
#define DH   64
#define NOUT 128

typedef float floatx4 __attribute__((ext_vector_type(4)));
typedef short shortx8 __attribute__((ext_vector_type(8)));
typedef unsigned short ushortx4 __attribute__((ext_vector_type(4)));

__device__ __forceinline__ unsigned short f2bf(float f) {
  unsigned int u = __float_as_uint(f);
  u += 0x7FFFu + ((u >> 16) & 1u);           // RTNE
  return (unsigned short)(u >> 16);
}
__device__ __forceinline__ float bf2f(unsigned short u) {
  return __uint_as_float(((unsigned int)u) << 16);
}
__device__ __forceinline__ floatx4 f4zero() { floatx4 v; v[0]=0.f;v[1]=0.f;v[2]=0.f;v[3]=0.f; return v; }
__device__ __forceinline__ shortx8 s8zero() { shortx8 v;
#pragma unroll
  for (int i=0;i<8;++i) v[i]=0; return v; }

// ---------------- k0: weight prep (bf16 + transpose) ----------------
__global__ __launch_bounds__(256) void k_wprep(
    const float* __restrict__ qkv_w, const float* __restrict__ cw1,
    const float* __restrict__ cw2, const float* __restrict__ dw,
    unsigned short* __restrict__ qwt, unsigned short* __restrict__ w1t,
    unsigned short* __restrict__ w2t, unsigned short* __restrict__ dwt)
{
  int o = blockIdx.x * 256 + threadIdx.x;
  if (o < 18432) {
    int co = o / 96, ci = o % 96;
    qwt[o] = f2bf(qkv_w[ci * 192 + co]);
  } else if (o < 43008) {
    int p = o - 18432;
    int tap = p / 8192, rem = p % 8192, co = rem >> 6, ci = rem & 63;
    w1t[p] = f2bf(cw1[(tap * 64 + ci) * 128 + co]);
  } else if (o < 92160) {
    int p = o - 43008;
    int tap = p / 16384, rem = p % 16384, co = rem >> 7, ci = rem & 127;
    w2t[p] = f2bf(cw2[(tap * 128 + ci) * 128 + co]);
  } else if (o < 104448) {
    int p = o - 92160;
    int co = p / 96, ci = p % 96;
    dwt[p] = f2bf(dw[ci * 128 + co]);
  }
}

// ---------------- k1: qkv projection, 32-row tiles; q pre-scaled; v transposed+packed ----------------
__global__ __launch_bounds__(256) void k_qkv(
    const float* __restrict__ x, const unsigned short* __restrict__ qwt,
    const float* __restrict__ qkv_b, const float* __restrict__ scale_p,
    unsigned short* __restrict__ qb, unsigned short* __restrict__ kb,
    unsigned short* __restrict__ vT)
{
  __shared__ __align__(16) unsigned short Xs[32][104];
  const int bx = blockIdx.x;
  const int b = bx >> 6, t0 = (bx & 63) * 32;
  const int tid = threadIdx.x, wave = tid >> 6, lane = tid & 63;
  const int l15 = lane & 15, quad = lane >> 4;
  const float scl2 = scale_p[0] * 1.4426950408889634f;

  for (int idx = tid; idx < 32 * 24; idx += 256) {
    int r = idx / 24, c = (idx % 24) * 4;
    float4 xv = *(const float4*)(x + ((size_t)(b * T_ + t0 + r)) * CIN + c);
    ushort4 o; o.x = f2bf(xv.x); o.y = f2bf(xv.y); o.z = f2bf(xv.z); o.w = f2bf(xv.w);
    *(ushort4*)(&Xs[r][c]) = o;
  }
  __syncthreads();

  floatx4 acc[2][3];
#pragma unroll
  for (int mt = 0; mt < 2; ++mt)
#pragma unroll
    for (int nt = 0; nt < 3; ++nt) acc[mt][nt] = f4zero();

#pragma unroll
  for (int ks = 0; ks < 3; ++ks) {
    shortx8 wf[3];
#pragma unroll
    for (int nt = 0; nt < 3; ++nt) {
      int j = wave * 48 + nt * 16 + l15;
      wf[nt] = *(const shortx8*)(qwt + (size_t)j * 96 + ks * 32 + quad * 8);
    }
#pragma unroll
    for (int mt = 0; mt < 2; ++mt) {
      shortx8 af = *(const shortx8*)(&Xs[mt * 16 + l15][ks * 32 + quad * 8]);
#pragma unroll
      for (int nt = 0; nt < 3; ++nt)
        acc[mt][nt] = __builtin_amdgcn_mfma_f32_16x16x32_bf16(af, wf[nt], acc[mt][nt], 0, 0, 0);
    }
  }

#pragma unroll
  for (int nt = 0; nt < 3; ++nt) {
    int j0 = wave * 48 + nt * 16;
    int j = j0 + l15;
    float bias = qkv_b[j];
    if (j0 < 128) {
#pragma unroll
      for (int mt = 0; mt < 2; ++mt)
#pragma unroll
        for (int r = 0; r < 4; ++r) {
          int t = t0 + mt * 16 + quad * 4 + r;
          float v = acc[mt][nt][r] + bias;
          if (j0 < 64) qb[((size_t)b * T_ + t) * DH + j] = f2bf(v * scl2);
          else         kb[((size_t)b * T_ + t) * DH + (j - 64)] = f2bf(v);
        }
    } else {
      int d = j - 128;
#pragma unroll
      for (int mt = 0; mt < 2; ++mt) {
        ushortx4 u;
        u[0] = f2bf(acc[mt][nt][0] + bias);
        u[1] = f2bf(acc[mt][nt][1] + bias);
        u[2] = f2bf(acc[mt][nt][2] + bias);
        u[3] = f2bf(acc[mt][nt][3] + bias);
        // FIX (r3 bug): b*DH batch offset was dropped in the packed rewrite.
        *(ushortx4*)(vT + ((size_t)b * DH + d) * T_ + t0 + mt * 16 + quad * 4) = u;
      }
    }
  }
}

// ---------------- k2: streaming attention, S^T trick, V-from-global, split-S 4-way ----------------
// Partials (bf16, unnormalized) -> opart[split][b][t][d] (aliases d_out); row-sums -> lws.
__global__ __launch_bounds__(256, 4) void k_attn(
    const unsigned short* __restrict__ qb, const unsigned short* __restrict__ kb,
    const unsigned short* __restrict__ vT,
    unsigned short* __restrict__ opart, float* __restrict__ lws)
{
  __shared__ __align__(16) unsigned short Kt[64][72];    // [s][d]
  __shared__ __align__(16) unsigned short Pt[4][16][72]; // per-wave [m][s]
  const int bx = blockIdx.x;
  const int half = bx & 3, qt = (bx >> 2) & 31, b = bx >> 7;
  const int tid = threadIdx.x, wave = tid >> 6, lane = tid & 63;
  const int l15 = lane & 15, quad = lane >> 4;

  const unsigned short* qrow = qb + ((size_t)b * T_ + qt * 64 + wave * 16 + l15) * DH;
  shortx8 qf0 = *(const shortx8*)(qrow + quad * 8);
  shortx8 qf1 = *(const shortx8*)(qrow + 32 + quad * 8);

  floatx4 O[5];
#pragma unroll
  for (int i = 0; i < 5; ++i) O[i] = f4zero();

  shortx8 ones;
#pragma unroll
  for (int i = 0; i < 8; ++i) ones[i] = (short)0x3F80;

  const unsigned short* kbase = kb + (size_t)b * T_ * DH + (size_t)half * 512 * DH;
  const unsigned short* vbase = vT + (size_t)b * DH * T_ + half * 512;

  const int kr0 = tid >> 3, kc = (tid & 7) * 8;
  shortx8 pk[2];
  pk[0] = *(const shortx8*)(kbase + (size_t)kr0 * DH + kc);
  pk[1] = *(const shortx8*)(kbase + (size_t)(kr0 + 32) * DH + kc);

  for (int t = 0; t < 8; ++t) {
    *(shortx8*)(&Kt[kr0][kc]) = pk[0];
    *(shortx8*)(&Kt[kr0 + 32][kc]) = pk[1];
    __syncthreads();
    const int s0 = t * 64;

    shortx8 bv[2][4];                        // V frags straight from global (L2-resident)
#pragma unroll
    for (int kk = 0; kk < 2; ++kk)
#pragma unroll
      for (int dt = 0; dt < 4; ++dt)
        bv[kk][dt] = *(const shortx8*)(vbase + (size_t)(dt * 16 + l15) * T_ + s0 + kk * 32 + quad * 8);

    if (t < 7) {                             // prefetch next K tile (regs)
      pk[0] = *(const shortx8*)(kbase + (size_t)(s0 + 64 + kr0) * DH + kc);
      pk[1] = *(const shortx8*)(kbase + (size_t)(s0 + 64 + kr0 + 32) * DH + kc);
    }

    floatx4 S[4];                            // S^T = mfma(A=K, B=Q): row=s, col=m
#pragma unroll
    for (int nt = 0; nt < 4; ++nt) {
      shortx8 bk0 = *(const shortx8*)(&Kt[nt * 16 + l15][quad * 8]);
      shortx8 bk1 = *(const shortx8*)(&Kt[nt * 16 + l15][32 + quad * 8]);
      S[nt] = __builtin_amdgcn_mfma_f32_16x16x32_bf16(bk0, qf0, f4zero(), 0, 0, 0);
      S[nt] = __builtin_amdgcn_mfma_f32_16x16x32_bf16(bk1, qf1, S[nt], 0, 0, 0);
    }

    // P = exp2(S^T); lane holds 4 consecutive s at fixed m -> one b64 write per nt
#pragma unroll
    for (int nt = 0; nt < 4; ++nt) {
      ushortx4 u;
      u[0] = f2bf(exp2f(S[nt][0]));
      u[1] = f2bf(exp2f(S[nt][1]));
      u[2] = f2bf(exp2f(S[nt][2]));
      u[3] = f2bf(exp2f(S[nt][3]));
      *(ushortx4*)(&Pt[wave][l15][nt * 16 + quad * 4]) = u;
    }
    asm volatile("" ::: "memory");           // keep P write->read program order

    // O += P.V ; l from ones B-frag (constant)
#pragma unroll
    for (int kk = 0; kk < 2; ++kk) {
      shortx8 ap = *(const shortx8*)(&Pt[wave][l15][kk * 32 + quad * 8]);
#pragma unroll
      for (int dt = 0; dt < 4; ++dt)
        O[dt] = __builtin_amdgcn_mfma_f32_16x16x32_bf16(ap, bv[kk][dt], O[dt], 0, 0, 0);
      O[4] = __builtin_amdgcn_mfma_f32_16x16x32_bf16(ap, ones, O[4], 0, 0, 0);
    }
    __syncthreads();                         // Kt consumed before restage
  }

  unsigned short* obase = opart + (((size_t)(half * B_ + b) * T_) + qt * 64 + wave * 16) * DH;
#pragma unroll
  for (int r = 0; r < 4; ++r) {
    int row = quad * 4 + r;
#pragma unroll
    for (int dt = 0; dt < 4; ++dt)
      obase[(size_t)row * DH + dt * 16 + l15] = f2bf(O[dt][r]);
    if (l15 == 0)
      lws[(half * B_ + b) * T_ + qt * 64 + wave * 16 + row] = O[4][r];
  }
}

// ---------------- k3: combine partials + conv1 + relu (32-row tiles) ----------------
__global__ __launch_bounds__(256) void k_conv1(
    const unsigned short* __restrict__ opart, const float* __restrict__ lws,
    const unsigned short* __restrict__ w1t, const float* __restrict__ b1,
    unsigned short* __restrict__ hb)
{
  __shared__ __align__(16) unsigned short At[34][72];
  const int bx = blockIdx.x;
  const int b = bx >> 6, t0 = (bx & 63) * 32;
  const int tid = threadIdx.x, wave = tid >> 6, lane = tid & 63;
  const int l15 = lane & 15, quad = lane >> 4;

  for (int idx = tid; idx < 34 * 8; idx += 256) {
    int r = idx >> 3, c = (idx & 7) * 8;
    int t = t0 + r - 1;
    shortx8 v = s8zero();
    if (t >= 0 && t < T_) {
      float a8[8];
#pragma unroll
      for (int e = 0; e < 8; ++e) a8[e] = 0.f;
      float lsum = 0.f;
#pragma unroll
      for (int s = 0; s < 4; ++s) {
        shortx8 u = *(const shortx8*)(opart + (((size_t)(s * B_ + b)) * T_ + t) * DH + c);
#pragma unroll
        for (int e = 0; e < 8; ++e) a8[e] += bf2f((unsigned short)u[e]);
        lsum += lws[(s * B_ + b) * T_ + t];
      }
      float inv = 1.f / lsum;
#pragma unroll
      for (int e = 0; e < 8; ++e) v[e] = (short)f2bf(a8[e] * inv);
    }
    *(shortx8*)(&At[r][c]) = v;
  }
  __syncthreads();

  floatx4 acc[2][2];
#pragma unroll
  for (int mt = 0; mt < 2; ++mt) { acc[mt][0] = f4zero(); acc[mt][1] = f4zero(); }

#pragma unroll
  for (int tap = 0; tap < 3; ++tap) {
#pragma unroll
    for (int ks = 0; ks < 2; ++ks) {
      shortx8 wf[2];
#pragma unroll
      for (int ct = 0; ct < 2; ++ct) {
        int co = wave * 32 + ct * 16 + l15;
        wf[ct] = *(const shortx8*)(w1t + ((size_t)tap * 128 + co) * 64 + ks * 32 + quad * 8);
      }
#pragma unroll
      for (int mt = 0; mt < 2; ++mt) {
        shortx8 af = *(const shortx8*)(&At[mt * 16 + l15 + tap][ks * 32 + quad * 8]);
        acc[mt][0] = __builtin_amdgcn_mfma_f32_16x16x32_bf16(af, wf[0], acc[mt][0], 0, 0, 0);
        acc[mt][1] = __builtin_amdgcn_mfma_f32_16x16x32_bf16(af, wf[1], acc[mt][1], 0, 0, 0);
      }
    }
  }

#pragma unroll
  for (int ct = 0; ct < 2; ++ct) {
    int co = wave * 32 + ct * 16 + l15;
    float bias = b1[co];
#pragma unroll
    for (int mt = 0; mt < 2; ++mt)
#pragma unroll
      for (int r = 0; r < 4; ++r) {
        int t = t0 + mt * 16 + quad * 4 + r;
        hb[((size_t)b * T_ + t) * NOUT + co] = f2bf(fmaxf(acc[mt][ct][r] + bias, 0.f));
      }
  }
}

// ---------------- k4: conv2 + relu + residual + relu (32-row tiles) ----------------
__global__ __launch_bounds__(256) void k_conv2(
    const unsigned short* __restrict__ hb, const float* __restrict__ x,
    const unsigned short* __restrict__ w2t, const unsigned short* __restrict__ dwt,
    const float* __restrict__ b2, float* __restrict__ out)
{
  __shared__ __align__(16) unsigned short Ht[34][136];
  __shared__ __align__(16) unsigned short Xt[32][104];
  const int bx = blockIdx.x;
  const int b = bx >> 6, t0 = (bx & 63) * 32;
  const int tid = threadIdx.x, wave = tid >> 6, lane = tid & 63;
  const int l15 = lane & 15, quad = lane >> 4;

  for (int idx = tid; idx < 34 * 16; idx += 256) {
    int r = idx >> 4, c = (idx & 15) * 8;
    int t = t0 + r - 1;
    shortx8 v = s8zero();
    if (t >= 0 && t < T_) v = *(const shortx8*)(hb + ((size_t)b * T_ + t) * NOUT + c);
    *(shortx8*)(&Ht[r][c]) = v;
  }
  for (int idx = tid; idx < 32 * 24; idx += 256) {
    int r = idx / 24, c = (idx % 24) * 4;
    float4 xv = *(const float4*)(x + ((size_t)(b * T_ + t0 + r)) * CIN + c);
    ushort4 o; o.x = f2bf(xv.x); o.y = f2bf(xv.y); o.z = f2bf(xv.z); o.w = f2bf(xv.w);
    *(ushort4*)(&Xt[r][c]) = o;
  }
  __syncthreads();

  floatx4 a2[2][2], ar[2][2];
#pragma unroll
  for (int mt = 0; mt < 2; ++mt) { a2[mt][0]=f4zero(); a2[mt][1]=f4zero(); ar[mt][0]=f4zero(); ar[mt][1]=f4zero(); }

#pragma unroll
  for (int tap = 0; tap < 3; ++tap) {
#pragma unroll
    for (int ks = 0; ks < 4; ++ks) {
      shortx8 wf[2];
#pragma unroll
      for (int ct = 0; ct < 2; ++ct) {
        int co = wave * 32 + ct * 16 + l15;
        wf[ct] = *(const shortx8*)(w2t + ((size_t)tap * 128 + co) * 128 + ks * 32 + quad * 8);
      }
#pragma unroll
      for (int mt = 0; mt < 2; ++mt) {
        shortx8 af = *(const shortx8*)(&Ht[mt * 16 + l15 + tap][ks * 32 + quad * 8]);
        a2[mt][0] = __builtin_amdgcn_mfma_f32_16x16x32_bf16(af, wf[0], a2[mt][0], 0, 0, 0);
        a2[mt][1] = __builtin_amdgcn_mfma_f32_16x16x32_bf16(af, wf[1], a2[mt][1], 0, 0, 0);
      }
    }
  }
#pragma unroll
  for (int ks = 0; ks < 3; ++ks) {
    shortx8 wf[2];
#pragma unroll
    for (int ct = 0; ct < 2; ++ct) {
      int co = wave * 32 + ct * 16 + l15;
      wf[ct] = *(const shortx8*)(dwt + (size_t)co * 96 + ks * 32 + quad * 8);
    }
#pragma unroll
    for (int mt = 0; mt < 2; ++mt) {
      shortx8 af = *(const shortx8*)(&Xt[mt * 16 + l15][ks * 32 + quad * 8]);
      ar[mt][0] = __builtin_amdgcn_mfma_f32_16x16x32_bf16(af, wf[0], ar[mt][0], 0, 0, 0);
      ar[mt][1] = __builtin_amdgcn_mfma_f32_16x16x32_bf16(af, wf[1], ar[mt][1], 0, 0, 0);
    }
  }

  const float kres = 1.0f + 1.0f / 2048.0f;   // res + en_res (weight_x == 1/T exactly)
#pragma unroll
  for (int ct = 0; ct < 2; ++ct) {
    int co = wave * 32 + ct * 16 + l15;
    float bias = b2[co];
#pragma unroll
    for (int mt = 0; mt < 2; ++mt)
#pragma unroll
      for (int r = 0; r < 4; ++r) {
        int t = t0 + mt * 16 + quad * 4 + r;
        float o2 = fmaxf(a2[mt][ct][r] + bias, 0.f);
        out[((size_t)b * T_ + t) * NOUT + co] = fmaxf(o2 + ar[mt][ct][r] * kres, 0.f);
      }
  }
}

// ---------------- launch ----------------
extern "C" void kernel_launch(void* const* d_in, const int* in_sizes, int n_in,
                              void* d_out, int out_size, void* d_ws, size_t ws_size,
                              hipStream_t stream) {
  const float* x      = (const float*)d_in[0];
  const float* qkv_w  = (const float*)d_in[1];
  const float* qkv_b  = (const float*)d_in[2];
  const float* scale  = (const float*)d_in[3];
  const float* cw1    = (const float*)d_in[4];
  const float* cb1    = (const float*)d_in[5];
  const float* cw2    = (const float*)d_in[6];
  const float* cb2    = (const float*)d_in[7];
  const float* dw     = (const float*)d_in[8];

  char* ws = (char*)d_ws;
  unsigned short* qb  = (unsigned short*)(ws + 0);          // [B,T,64] bf16
  unsigned short* kb  = (unsigned short*)(ws + 4194304);    // [B,T,64] bf16
  unsigned short* vT  = (unsigned short*)(ws + 8388608);    // [B,64,T] bf16
  unsigned short* hb  = (unsigned short*)(ws + 12582912);   // [B,T,128] bf16
  unsigned short* qwt = (unsigned short*)(ws + 20971520);   // [192][96]
  unsigned short* w1t = (unsigned short*)(ws + 21008384);   // [3][128][64]
  unsigned short* w2t = (unsigned short*)(ws + 21057536);   // [3][128][128]
  unsigned short* dwt = (unsigned short*)(ws + 21155840);   // [128][96]
  float*          lws = (float*)(ws + 21180416);            // [4][B,T] row-sums

  unsigned short* opart = (unsigned short*)d_out;  // [4][B,T,64] bf16 partials (== d_out bytes)

  k_wprep<<<408, 256, 0, stream>>>(qkv_w, cw1, cw2, dw, qwt, w1t, w2t, dwt);
  k_qkv  <<<1024, 256, 0, stream>>>(x, qwt, qkv_b, scale, qb, kb, vT);
  k_attn <<<2048, 256, 0, stream>>>(qb, kb, vT, opart, lws);
  k_conv1<<<1024, 256, 0, stream>>>(opart, lws, w1t, cb1, hb);
  k_conv2<<<1024, 256, 0, stream>>>(hb, x, w2t, dwt, cb2, (float*)d_out);
}

// Round 8
// 181.976 us; speedup vs baseline: 1.0281x; 1.0281x over previous
//
#include <hip/hip_runtime.h>
#include <cstdint>

#define B_   16
#define T_   2048
#define CIN  96
#define DH   64
#define NOUT 128

typedef float floatx4 __attribute__((ext_vector_type(4)));
typedef short shortx8 __attribute__((ext_vector_type(8)));
typedef unsigned short ushortx4 __attribute__((ext_vector_type(4)));

__device__ __forceinline__ unsigned short f2bf(float f) {
  unsigned int u = __float_as_uint(f);
  u += 0x7FFFu + ((u >> 16) & 1u);           // RTNE
  return (unsigned short)(u >> 16);
}
__device__ __forceinline__ float bf2f(unsigned short u) {
  return __uint_as_float(((unsigned int)u) << 16);
}
__device__ __forceinline__ floatx4 f4zero() { floatx4 v; v[0]=0.f;v[1]=0.f;v[2]=0.f;v[3]=0.f; return v; }
__device__ __forceinline__ shortx8 s8zero() { shortx8 v;
#pragma unroll
  for (int i=0;i<8;++i) v[i]=0; return v; }

// ---------------- k0: weight prep (bf16 + transpose) ----------------
__global__ __launch_bounds__(256) void k_wprep(
    const float* __restrict__ qkv_w, const float* __restrict__ cw1,
    const float* __restrict__ cw2, const float* __restrict__ dw,
    unsigned short* __restrict__ qwt, unsigned short* __restrict__ w1t,
    unsigned short* __restrict__ w2t, unsigned short* __restrict__ dwt)
{
  int o = blockIdx.x * 256 + threadIdx.x;
  if (o < 18432) {
    int co = o / 96, ci = o % 96;
    qwt[o] = f2bf(qkv_w[ci * 192 + co]);
  } else if (o < 43008) {
    int p = o - 18432;
    int tap = p / 8192, rem = p % 8192, co = rem >> 6, ci = rem & 63;
    w1t[p] = f2bf(cw1[(tap * 64 + ci) * 128 + co]);
  } else if (o < 92160) {
    int p = o - 43008;
    int tap = p / 16384, rem = p % 16384, co = rem >> 7, ci = rem & 127;
    w2t[p] = f2bf(cw2[(tap * 128 + ci) * 128 + co]);
  } else if (o < 104448) {
    int p = o - 92160;
    int co = p / 96, ci = p % 96;
    dwt[p] = f2bf(dw[ci * 128 + co]);
  }
}

// ---------------- k1: qkv projection, 32-row tiles; q pre-scaled; v transposed+packed ----------------
__global__ __launch_bounds__(256) void k_qkv(
    const float* __restrict__ x, const unsigned short* __restrict__ qwt,
    const float* __restrict__ qkv_b, const float* __restrict__ scale_p,
    unsigned short* __restrict__ qb, unsigned short* __restrict__ kb,
    unsigned short* __restrict__ vT)
{
  __shared__ __align__(16) unsigned short Xs[32][104];
  const int bx = blockIdx.x;
  const int b = bx >> 6, t0 = (bx & 63) * 32;
  const int tid = threadIdx.x, wave = tid >> 6, lane = tid & 63;
  const int l15 = lane & 15, quad = lane >> 4;
  const float scl2 = scale_p[0] * 1.4426950408889634f;

  for (int idx = tid; idx < 32 * 24; idx += 256) {
    int r = idx / 24, c = (idx % 24) * 4;
    float4 xv = *(const float4*)(x + ((size_t)(b * T_ + t0 + r)) * CIN + c);
    ushort4 o; o.x = f2bf(xv.x); o.y = f2bf(xv.y); o.z = f2bf(xv.z); o.w = f2bf(xv.w);
    *(ushort4*)(&Xs[r][c]) = o;
  }
  __syncthreads();

  floatx4 acc[2][3];
#pragma unroll
  for (int mt = 0; mt < 2; ++mt)
#pragma unroll
    for (int nt = 0; nt < 3; ++nt) acc[mt][nt] = f4zero();

#pragma unroll
  for (int ks = 0; ks < 3; ++ks) {
    shortx8 wf[3];
#pragma unroll
    for (int nt = 0; nt < 3; ++nt) {
      int j = wave * 48 + nt * 16 + l15;
      wf[nt] = *(const shortx8*)(qwt + (size_t)j * 96 + ks * 32 + quad * 8);
    }
#pragma unroll
    for (int mt = 0; mt < 2; ++mt) {
      shortx8 af = *(const shortx8*)(&Xs[mt * 16 + l15][ks * 32 + quad * 8]);
#pragma unroll
      for (int nt = 0; nt < 3; ++nt)
        acc[mt][nt] = __builtin_amdgcn_mfma_f32_16x16x32_bf16(af, wf[nt], acc[mt][nt], 0, 0, 0);
    }
  }

#pragma unroll
  for (int nt = 0; nt < 3; ++nt) {
    int j0 = wave * 48 + nt * 16;
    int j = j0 + l15;
    float bias = qkv_b[j];
    if (j0 < 128) {
#pragma unroll
      for (int mt = 0; mt < 2; ++mt)
#pragma unroll
        for (int r = 0; r < 4; ++r) {
          int t = t0 + mt * 16 + quad * 4 + r;
          float v = acc[mt][nt][r] + bias;
          if (j0 < 64) qb[((size_t)b * T_ + t) * DH + j] = f2bf(v * scl2);
          else         kb[((size_t)b * T_ + t) * DH + (j - 64)] = f2bf(v);
        }
    } else {
      int d = j - 128;
#pragma unroll
      for (int mt = 0; mt < 2; ++mt) {
        ushortx4 u;
        u[0] = f2bf(acc[mt][nt][0] + bias);
        u[1] = f2bf(acc[mt][nt][1] + bias);
        u[2] = f2bf(acc[mt][nt][2] + bias);
        u[3] = f2bf(acc[mt][nt][3] + bias);
        *(ushortx4*)(vT + ((size_t)b * DH + d) * T_ + t0 + mt * 16 + quad * 4) = u;
      }
    }
  }
}

// ---------------- k2: BARRIER-FREE streaming attention ----------------
// Each wave autonomously owns 32 q-rows (2 m-tiles) x 512 s (split-4).
// K and V fragments load straight from global (S^T A-frag pattern == kb's
// row-major layout); only LDS use is the per-wave P round-trip (intra-wave,
// ordered by the in-order DS pipe + compiler fences). No __syncthreads at all.
__global__ __launch_bounds__(256, 3) void k_attn(
    const unsigned short* __restrict__ qb, const unsigned short* __restrict__ kb,
    const unsigned short* __restrict__ vT,
    unsigned short* __restrict__ opart, float* __restrict__ lws)
{
  __shared__ __align__(16) unsigned short Pt[4][2][16][72]; // [wave][mt][m][s]
  const int bx = blockIdx.x;
  const int h2 = bx & 1, qt = (bx >> 1) & 31, b = bx >> 6;
  const int tid = threadIdx.x, wave = tid >> 6, lane = tid & 63;
  const int l15 = lane & 15, quad = lane >> 4;
  const int mhalf = wave & 1, split = h2 * 2 + (wave >> 1);

  const int qrow0 = qt * 64 + mhalf * 32;
  const unsigned short* qbase = qb + ((size_t)b * T_ + qrow0) * DH;
  shortx8 qf[2][2];
#pragma unroll
  for (int mt = 0; mt < 2; ++mt) {
    qf[mt][0] = *(const shortx8*)(qbase + (size_t)(mt * 16 + l15) * DH + quad * 8);
    qf[mt][1] = *(const shortx8*)(qbase + (size_t)(mt * 16 + l15) * DH + 32 + quad * 8);
  }

  floatx4 O[2][5];
#pragma unroll
  for (int mt = 0; mt < 2; ++mt)
#pragma unroll
    for (int i = 0; i < 5; ++i) O[mt][i] = f4zero();

  shortx8 ones;
#pragma unroll
  for (int i = 0; i < 8; ++i) ones[i] = (short)0x3F80;

  const unsigned short* kbase = kb + (size_t)b * T_ * DH + (size_t)split * 512 * DH;
  const unsigned short* vbase = vT + (size_t)b * DH * T_ + split * 512;

  for (int t = 0; t < 8; ++t) {
    const int s0 = t * 64;

    shortx8 bk[4][2], bv[2][4];              // 16 global b128 loads, all issued up front
#pragma unroll
    for (int nt = 0; nt < 4; ++nt) {
      bk[nt][0] = *(const shortx8*)(kbase + (size_t)(s0 + nt * 16 + l15) * DH + quad * 8);
      bk[nt][1] = *(const shortx8*)(kbase + (size_t)(s0 + nt * 16 + l15) * DH + 32 + quad * 8);
    }
#pragma unroll
    for (int kk = 0; kk < 2; ++kk)
#pragma unroll
      for (int dt = 0; dt < 4; ++dt)
        bv[kk][dt] = *(const shortx8*)(vbase + (size_t)(dt * 16 + l15) * T_ + s0 + kk * 32 + quad * 8);

    // S^T = mfma(A=K, B=Q): row=s-sub, col=m; exp2 + truncate-pack -> LDS b64
#pragma unroll
    for (int mt = 0; mt < 2; ++mt) {
      floatx4 S[4];
#pragma unroll
      for (int nt = 0; nt < 4; ++nt) {
        S[nt] = __builtin_amdgcn_mfma_f32_16x16x32_bf16(bk[nt][0], qf[mt][0], f4zero(), 0, 0, 0);
        S[nt] = __builtin_amdgcn_mfma_f32_16x16x32_bf16(bk[nt][1], qf[mt][1], S[nt], 0, 0, 0);
      }
#pragma unroll
      for (int nt = 0; nt < 4; ++nt) {
        ushortx4 u;                           // truncation (not RTNE): bias cancels in O/l
        u[0] = (unsigned short)(__float_as_uint(exp2f(S[nt][0])) >> 16);
        u[1] = (unsigned short)(__float_as_uint(exp2f(S[nt][1])) >> 16);
        u[2] = (unsigned short)(__float_as_uint(exp2f(S[nt][2])) >> 16);
        u[3] = (unsigned short)(__float_as_uint(exp2f(S[nt][3])) >> 16);
        *(ushortx4*)(&Pt[wave][mt][l15][nt * 16 + quad * 4]) = u;
      }
    }
    asm volatile("" ::: "memory");           // P writes before P reads (program order)

#pragma unroll
    for (int mt = 0; mt < 2; ++mt) {
#pragma unroll
      for (int kk = 0; kk < 2; ++kk) {
        shortx8 ap = *(const shortx8*)(&Pt[wave][mt][l15][kk * 32 + quad * 8]);
#pragma unroll
        for (int dt = 0; dt < 4; ++dt)
          O[mt][dt] = __builtin_amdgcn_mfma_f32_16x16x32_bf16(ap, bv[kk][dt], O[mt][dt], 0, 0, 0);
        O[mt][4] = __builtin_amdgcn_mfma_f32_16x16x32_bf16(ap, ones, O[mt][4], 0, 0, 0);
      }
    }
    asm volatile("" ::: "memory");           // P reads before next tile's P writes
  }

#pragma unroll
  for (int mt = 0; mt < 2; ++mt) {
    unsigned short* obase = opart + (((size_t)(split * B_ + b) * T_) + qrow0 + mt * 16) * DH;
#pragma unroll
    for (int r = 0; r < 4; ++r) {
      int row = quad * 4 + r;
#pragma unroll
      for (int dt = 0; dt < 4; ++dt)
        obase[(size_t)row * DH + dt * 16 + l15] = f2bf(O[mt][dt][r]);
      if (l15 == 0)
        lws[(split * B_ + b) * T_ + qrow0 + mt * 16 + row] = O[mt][4][r];
    }
  }
}

// ---------------- k3: combine partials + conv1 + relu (32-row tiles) ----------------
__global__ __launch_bounds__(256) void k_conv1(
    const unsigned short* __restrict__ opart, const float* __restrict__ lws,
    const unsigned short* __restrict__ w1t, const float* __restrict__ b1,
    unsigned short* __restrict__ hb)
{
  __shared__ __align__(16) unsigned short At[34][72];
  const int bx = blockIdx.x;
  const int b = bx >> 6, t0 = (bx & 63) * 32;
  const int tid = threadIdx.x, wave = tid >> 6, lane = tid & 63;
  const int l15 = lane & 15, quad = lane >> 4;

  for (int idx = tid; idx < 34 * 8; idx += 256) {
    int r = idx >> 3, c = (idx & 7) * 8;
    int t = t0 + r - 1;
    shortx8 v = s8zero();
    if (t >= 0 && t < T_) {
      float a8[8];
#pragma unroll
      for (int e = 0; e < 8; ++e) a8[e] = 0.f;
      float lsum = 0.f;
#pragma unroll
      for (int s = 0; s < 4; ++s) {
        shortx8 u = *(const shortx8*)(opart + (((size_t)(s * B_ + b)) * T_ + t) * DH + c);
#pragma unroll
        for (int e = 0; e < 8; ++e) a8[e] += bf2f((unsigned short)u[e]);
        lsum += lws[(s * B_ + b) * T_ + t];
      }
      float inv = 1.f / lsum;
#pragma unroll
      for (int e = 0; e < 8; ++e) v[e] = (short)f2bf(a8[e] * inv);
    }
    *(shortx8*)(&At[r][c]) = v;
  }
  __syncthreads();

  floatx4 acc[2][2];
#pragma unroll
  for (int mt = 0; mt < 2; ++mt) { acc[mt][0] = f4zero(); acc[mt][1] = f4zero(); }

#pragma unroll
  for (int tap = 0; tap < 3; ++tap) {
#pragma unroll
    for (int ks = 0; ks < 2; ++ks) {
      shortx8 wf[2];
#pragma unroll
      for (int ct = 0; ct < 2; ++ct) {
        int co = wave * 32 + ct * 16 + l15;
        wf[ct] = *(const shortx8*)(w1t + ((size_t)tap * 128 + co) * 64 + ks * 32 + quad * 8);
      }
#pragma unroll
      for (int mt = 0; mt < 2; ++mt) {
        shortx8 af = *(const shortx8*)(&At[mt * 16 + l15 + tap][ks * 32 + quad * 8]);
        acc[mt][0] = __builtin_amdgcn_mfma_f32_16x16x32_bf16(af, wf[0], acc[mt][0], 0, 0, 0);
        acc[mt][1] = __builtin_amdgcn_mfma_f32_16x16x32_bf16(af, wf[1], acc[mt][1], 0, 0, 0);
      }
    }
  }

#pragma unroll
  for (int ct = 0; ct < 2; ++ct) {
    int co = wave * 32 + ct * 16 + l15;
    float bias = b1[co];
#pragma unroll
    for (int mt = 0; mt < 2; ++mt)
#pragma unroll
      for (int r = 0; r < 4; ++r) {
        int t = t0 + mt * 16 + quad * 4 + r;
        hb[((size_t)b * T_ + t) * NOUT + co] = f2bf(fmaxf(acc[mt][ct][r] + bias, 0.f));
      }
  }
}

// ---------------- k4: conv2 + relu + residual + relu (32-row tiles) ----------------
__global__ __launch_bounds__(256) void k_conv2(
    const unsigned short* __restrict__ hb, const float* __restrict__ x,
    const unsigned short* __restrict__ w2t, const unsigned short* __restrict__ dwt,
    const float* __restrict__ b2, float* __restrict__ out)
{
  __shared__ __align__(16) unsigned short Ht[34][136];
  __shared__ __align__(16) unsigned short Xt[32][104];
  const int bx = blockIdx.x;
  const int b = bx >> 6, t0 = (bx & 63) * 32;
  const int tid = threadIdx.x, wave = tid >> 6, lane = tid & 63;
  const int l15 = lane & 15, quad = lane >> 4;

  for (int idx = tid; idx < 34 * 16; idx += 256) {
    int r = idx >> 4, c = (idx & 15) * 8;
    int t = t0 + r - 1;
    shortx8 v = s8zero();
    if (t >= 0 && t < T_) v = *(const shortx8*)(hb + ((size_t)b * T_ + t) * NOUT + c);
    *(shortx8*)(&Ht[r][c]) = v;
  }
  for (int idx = tid; idx < 32 * 24; idx += 256) {
    int r = idx / 24, c = (idx % 24) * 4;
    float4 xv = *(const float4*)(x + ((size_t)(b * T_ + t0 + r)) * CIN + c);
    ushort4 o; o.x = f2bf(xv.x); o.y = f2bf(xv.y); o.z = f2bf(xv.z); o.w = f2bf(xv.w);
    *(ushort4*)(&Xt[r][c]) = o;
  }
  __syncthreads();

  floatx4 a2[2][2], ar[2][2];
#pragma unroll
  for (int mt = 0; mt < 2; ++mt) { a2[mt][0]=f4zero(); a2[mt][1]=f4zero(); ar[mt][0]=f4zero(); ar[mt][1]=f4zero(); }

#pragma unroll
  for (int tap = 0; tap < 3; ++tap) {
#pragma unroll
    for (int ks = 0; ks < 4; ++ks) {
      shortx8 wf[2];
#pragma unroll
      for (int ct = 0; ct < 2; ++ct) {
        int co = wave * 32 + ct * 16 + l15;
        wf[ct] = *(const shortx8*)(w2t + ((size_t)tap * 128 + co) * 128 + ks * 32 + quad * 8);
      }
#pragma unroll
      for (int mt = 0; mt < 2; ++mt) {
        shortx8 af = *(const shortx8*)(&Ht[mt * 16 + l15 + tap][ks * 32 + quad * 8]);
        a2[mt][0] = __builtin_amdgcn_mfma_f32_16x16x32_bf16(af, wf[0], a2[mt][0], 0, 0, 0);
        a2[mt][1] = __builtin_amdgcn_mfma_f32_16x16x32_bf16(af, wf[1], a2[mt][1], 0, 0, 0);
      }
    }
  }
#pragma unroll
  for (int ks = 0; ks < 3; ++ks) {
    shortx8 wf[2];
#pragma unroll
    for (int ct = 0; ct < 2; ++ct) {
      int co = wave * 32 + ct * 16 + l15;
      wf[ct] = *(const shortx8*)(dwt + (size_t)co * 96 + ks * 32 + quad * 8);
    }
#pragma unroll
    for (int mt = 0; mt < 2; ++mt) {
      shortx8 af = *(const shortx8*)(&Xt[mt * 16 + l15][ks * 32 + quad * 8]);
      ar[mt][0] = __builtin_amdgcn_mfma_f32_16x16x32_bf16(af, wf[0], ar[mt][0], 0, 0, 0);
      ar[mt][1] = __builtin_amdgcn_mfma_f32_16x16x32_bf16(af, wf[1], ar[mt][1], 0, 0, 0);
    }
  }

  const float kres = 1.0f + 1.0f / 2048.0f;   // res + en_res (weight_x == 1/T exactly)
#pragma unroll
  for (int ct = 0; ct < 2; ++ct) {
    int co = wave * 32 + ct * 16 + l15;
    float bias = b2[co];
#pragma unroll
    for (int mt = 0; mt < 2; ++mt)
#pragma unroll
      for (int r = 0; r < 4; ++r) {
        int t = t0 + mt * 16 + quad * 4 + r;
        float o2 = fmaxf(a2[mt][ct][r] + bias, 0.f);
        out[((size_t)b * T_ + t) * NOUT + co] = fmaxf(o2 + ar[mt][ct][r] * kres, 0.f);
      }
  }
}

// ---------------- launch ----------------
extern "C" void kernel_launch(void* const* d_in, const int* in_sizes, int n_in,
                              void* d_out, int out_size, void* d_ws, size_t ws_size,
                              hipStream_t stream) {
  const float* x      = (const float*)d_in[0];
  const float* qkv_w  = (const float*)d_in[1];
  const float* qkv_b  = (const float*)d_in[2];
  const float* scale  = (const float*)d_in[3];
  const float* cw1    = (const float*)d_in[4];
  const float* cb1    = (const float*)d_in[5];
  const float* cw2    = (const float*)d_in[6];
  const float* cb2    = (const float*)d_in[7];
  const float* dw     = (const float*)d_in[8];

  char* ws = (char*)d_ws;
  unsigned short* qb  = (unsigned short*)(ws + 0);          // [B,T,64] bf16
  unsigned short* kb  = (unsigned short*)(ws + 4194304);    // [B,T,64] bf16
  unsigned short* vT  = (unsigned short*)(ws + 8388608);    // [B,64,T] bf16
  unsigned short* hb  = (unsigned short*)(ws + 12582912);   // [B,T,128] bf16
  unsigned short* qwt = (unsigned short*)(ws + 20971520);   // [192][96]
  unsigned short* w1t = (unsigned short*)(ws + 21008384);   // [3][128][64]
  unsigned short* w2t = (unsigned short*)(ws + 21057536);   // [3][128][128]
  unsigned short* dwt = (unsigned short*)(ws + 21155840);   // [128][96]
  float*          lws = (float*)(ws + 21180416);            // [4][B,T] row-sums

  unsigned short* opart = (unsigned short*)d_out;  // [4][B,T,64] bf16 partials (== d_out bytes)

  k_wprep<<<408, 256, 0, stream>>>(qkv_w, cw1, cw2, dw, qwt, w1t, w2t, dwt);
  k_qkv  <<<1024, 256, 0, stream>>>(x, qwt, qkv_b, scale, qb, kb, vT);
  k_attn <<<1024, 256, 0, stream>>>(qb, kb, vT, opart, lws);
  k_conv1<<<1024, 256, 0, stream>>>(opart, lws, w1t, cb1, hb);
  k_conv2<<<1024, 256, 0, stream>>>(hb, x, w2t, dwt, cb2, (float*)d_out);
}